// Round 1
// baseline (853.349 us; speedup 1.0000x reference)
//
#include <hip/hip_runtime.h>
#include <math.h>

#define B_    4
#define CIN_  32
#define COUT_ 64
#define H_    192
#define W_    192
#define HW_   (H_ * W_)        // 36864
#define NPIX_ (B_ * HW_)       // 147456
#define EPS_  1e-5f

// ---------------------------------------------------------------------------
// Kernel 1: offsets = conv3x3_same(x, w_off) + b_off   (32 -> 18 channels)
// One thread per pixel, acc[18] (padded to 20 for float4 LDS reads).
// Also zeroes the stats accumulators (block 0) for the later stats kernel.
// ---------------------------------------------------------------------------
__global__ __launch_bounds__(256) void k_conv_off(
    const float* __restrict__ x, const float* __restrict__ w_off,
    const float* __restrict__ b_off, float* __restrict__ offs,
    float* __restrict__ stats)
{
    // LDS weights, transposed to [kk][ci][o], row padded 18 -> 20 floats
    __shared__ float wl[9 * 32 * 20];
    const int tid = threadIdx.x;
    for (int d = tid; d < 9 * 32 * 18; d += 256) {
        int o  = d % 18;
        int t2 = d / 18;
        int ci = t2 % 32;
        int kk = t2 / 32;
        // w_off layout (O=18, CI=32, 3, 3): [o][ci][kk]
        wl[(kk * 32 + ci) * 20 + o] = w_off[(o * 32 + ci) * 9 + kk];
    }
    for (int d = tid; d < 9 * 32; d += 256) {
        wl[d * 20 + 18] = 0.f;
        wl[d * 20 + 19] = 0.f;
    }
    if (blockIdx.x == 0) {
        for (int d = tid; d < 512; d += 256) stats[d] = 0.f;  // sum_bc + sumsq_bc
    }
    __syncthreads();

    const int pid = blockIdx.x * 256 + tid;           // < 147456
    const int b   = pid / HW_;
    const int rem = pid - b * HW_;
    const int h   = rem / W_;
    const int w   = rem - h * W_;

    float acc[20];
#pragma unroll
    for (int o = 0; o < 20; ++o) acc[o] = 0.f;

    const float* xb = x + b * CIN_ * HW_;
#pragma unroll 1
    for (int kk = 0; kk < 9; ++kk) {
        const int yy = h + kk / 3 - 1;
        const int xx = w + kk % 3 - 1;
        if (yy < 0 || yy >= H_ || xx < 0 || xx >= W_) continue;  // zero pad
        const float* xp = xb + yy * W_ + xx;
#pragma unroll 4
        for (int ci = 0; ci < 32; ++ci) {
            const float  xv = xp[ci * HW_];
            const float4* wr = (const float4*)&wl[(kk * 32 + ci) * 20];
#pragma unroll
            for (int q = 0; q < 5; ++q) {
                float4 wv = wr[q];
                acc[q * 4 + 0] += xv * wv.x;
                acc[q * 4 + 1] += xv * wv.y;
                acc[q * 4 + 2] += xv * wv.z;
                acc[q * 4 + 3] += xv * wv.w;
            }
        }
    }
#pragma unroll
    for (int o = 0; o < 18; ++o)
        offs[(b * 18 + o) * HW_ + rem] = acc[o] + b_off[o];
}

// ---------------------------------------------------------------------------
// Kernel 2: deformable conv. One thread per pixel, acc[64] in VGPRs.
// w_def transposed to [kk][c][o] in LDS (73.7 KB), read as float4 broadcast.
// Writes y = deform(x) + b_def  (B,64,H,W).
// ---------------------------------------------------------------------------
__global__ __launch_bounds__(256) void k_deform(
    const float* __restrict__ x, const float* __restrict__ offs,
    const float* __restrict__ w_def, const float* __restrict__ b_def,
    float* __restrict__ y)
{
    __shared__ float wl[9 * 32 * 64];   // 73728 B
    const int tid = threadIdx.x;
    for (int d = tid; d < 9 * 32 * 64; d += 256) {
        int o  = d & 63;
        int t2 = d >> 6;
        int c  = t2 % 32;
        int kk = t2 / 32;
        // w_def layout (O=64, C=32, 3, 3): [o][c][kk]
        wl[d] = w_def[(o * 32 + c) * 9 + kk];
    }
    __syncthreads();

    const int pid = blockIdx.x * 256 + tid;
    const int b   = pid / HW_;
    const int rem = pid - b * HW_;
    const int h   = rem / W_;
    const int w   = rem - h * W_;

    float acc[64];
#pragma unroll
    for (int o = 0; o < 64; ++o) acc[o] = 0.f;

    const float* xb = x + b * CIN_ * HW_;
    const float* ob = offs + b * 18 * HW_ + rem;

#pragma unroll 1
    for (int kk = 0; kk < 9; ++kk) {
        const float dy = ob[(2 * kk) * HW_];
        const float dx = ob[(2 * kk + 1) * HW_];
        const float py = (float)(h + kk / 3 - 1) + dy;
        const float px = (float)(w + kk % 3 - 1) + dx;
        const float y0f = floorf(py), x0f = floorf(px);
        const float wy = py - y0f, wx = px - x0f;
        const int iy0 = (int)y0f, ix0 = (int)x0f;
        const int iy1 = iy0 + 1,  ix1 = ix0 + 1;
        const float vy0 = (iy0 >= 0 && iy0 < H_) ? 1.f : 0.f;
        const float vy1 = (iy1 >= 0 && iy1 < H_) ? 1.f : 0.f;
        const float vx0 = (ix0 >= 0 && ix0 < W_) ? 1.f : 0.f;
        const float vx1 = (ix1 >= 0 && ix1 < W_) ? 1.f : 0.f;
        const float w00 = (1.f - wy) * (1.f - wx) * vy0 * vx0;
        const float w01 = (1.f - wy) * wx * vy0 * vx1;
        const float w10 = wy * (1.f - wx) * vy1 * vx0;
        const float w11 = wy * wx * vy1 * vx1;
        const int cy0 = min(max(iy0, 0), H_ - 1), cy1 = min(max(iy1, 0), H_ - 1);
        const int cx0 = min(max(ix0, 0), W_ - 1), cx1 = min(max(ix1, 0), W_ - 1);
        const int i00 = cy0 * W_ + cx0, i01 = cy0 * W_ + cx1;
        const int i10 = cy1 * W_ + cx0, i11 = cy1 * W_ + cx1;

        const float* wbase = &wl[(kk * 32) * 64];
#pragma unroll 4
        for (int c = 0; c < 32; ++c) {
            const float* xc = xb + c * HW_;
            const float  v  = w00 * xc[i00] + w01 * xc[i01] +
                              w10 * xc[i10] + w11 * xc[i11];
            const float4* wr = (const float4*)(wbase + c * 64);
#pragma unroll
            for (int q = 0; q < 16; ++q) {
                float4 wv = wr[q];
                acc[q * 4 + 0] += v * wv.x;
                acc[q * 4 + 1] += v * wv.y;
                acc[q * 4 + 2] += v * wv.z;
                acc[q * 4 + 3] += v * wv.w;
            }
        }
    }

    float* yp = y + b * COUT_ * HW_ + rem;
#pragma unroll
    for (int o = 0; o < 64; ++o) yp[o * HW_] = acc[o] + b_def[o];
}

// ---------------------------------------------------------------------------
// Kernel 3: per-(b,c) sum and sum-of-squares of y. Each 256-thread block
// covers one contiguous 256-elem slice, entirely inside one (b,c) plane
// (36864 % 256 == 0), so one atomicAdd pair per block.
// ---------------------------------------------------------------------------
__global__ __launch_bounds__(256) void k_stats(
    const float* __restrict__ y,
    float* __restrict__ sum_bc, float* __restrict__ sumsq_bc)
{
    const int pid = blockIdx.x * 256 + threadIdx.x;
    const float v = y[pid];
    float s = v, q = v * v;
#pragma unroll
    for (int off = 32; off; off >>= 1) {
        s += __shfl_xor(s, off, 64);
        q += __shfl_xor(q, off, 64);
    }
    __shared__ float ls[4], lq[4];
    const int lane = threadIdx.x & 63, wid = threadIdx.x >> 6;
    if (lane == 0) { ls[wid] = s; lq[wid] = q; }
    __syncthreads();
    if (threadIdx.x == 0) {
        const float ts = ls[0] + ls[1] + ls[2] + ls[3];
        const float tq = lq[0] + lq[1] + lq[2] + lq[3];
        const int bc = pid / HW_;  // uniform within block
        atomicAdd(&sum_bc[bc], ts);
        atomicAdd(&sumsq_bc[bc], tq);
    }
}

// ---------------------------------------------------------------------------
// Kernel 4 (1 block, 256 threads): BN statistics + SE MLP, folded into a
// per-(b,c) affine:  y_final_pre_relu = y * alpha[b,c] + bbias[b,c].
// thread = b*64 + c.
// ---------------------------------------------------------------------------
__global__ __launch_bounds__(256) void k_se(
    const float* __restrict__ sum_bc, const float* __restrict__ sumsq_bc,
    const float* __restrict__ gamma, const float* __restrict__ beta,
    const float* __restrict__ fc1_w, const float* __restrict__ fc1_b,
    const float* __restrict__ fc2_w, const float* __restrict__ fc2_b,
    float* __restrict__ alpha, float* __restrict__ bbias)
{
    const int tid = threadIdx.x;
    const int b = tid >> 6, c = tid & 63;

    float ch_s = 0.f, ch_q = 0.f;
#pragma unroll
    for (int bb = 0; bb < 4; ++bb) {
        ch_s += sum_bc[bb * 64 + c];
        ch_q += sumsq_bc[bb * 64 + c];
    }
    const float invN = 1.f / (float)(B_ * HW_);
    const float mean = ch_s * invN;
    const float var  = ch_q * invN - mean * mean;
    const float a    = gamma[c] * rsqrtf(var + EPS_);
    const float bi   = beta[c] - mean * a;

    __shared__ float sin_[256];     // BN'd per-(b,c) spatial mean
    sin_[tid] = a * (sum_bc[tid] * (1.f / (float)HW_)) + bi;
    __syncthreads();

    float hv[4];
#pragma unroll
    for (int j = 0; j < 4; ++j) {
        float hs = fc1_b[j];
        for (int cc = 0; cc < 64; ++cc) hs += sin_[b * 64 + cc] * fc1_w[j * 64 + cc];
        hv[j] = fmaxf(hs, 0.f);
    }
    float o = fc2_b[c];
#pragma unroll
    for (int j = 0; j < 4; ++j) o += hv[j] * fc2_w[c * 4 + j];
    const float s = 1.f / (1.f + expf(-o));

    alpha[tid] = a * s;
    bbias[tid] = bi * s;
}

// ---------------------------------------------------------------------------
// Kernel 5: fused affine(BN*SE) + ReLU + 2x2 maxpool -> out (4,64,96,96).
// One thread per output element; float2 loads of the two row pairs.
// ---------------------------------------------------------------------------
__global__ __launch_bounds__(256) void k_finish(
    const float* __restrict__ y,
    const float* __restrict__ alpha, const float* __restrict__ bbias,
    float* __restrict__ out)
{
    const int pid = blockIdx.x * 256 + threadIdx.x;  // < 4*64*96*96
    const int bc  = pid / (96 * 96);
    const int rem = pid - bc * (96 * 96);
    const int oh  = rem / 96, ow = rem - oh * 96;
    const float al = alpha[bc], bb = bbias[bc];
    const float* yp = y + bc * HW_ + (2 * oh) * W_ + 2 * ow;
    const float2 r0 = *(const float2*)yp;
    const float2 r1 = *(const float2*)(yp + W_);
    const float m0 = fmaxf(fmaf(r0.x, al, bb), fmaf(r0.y, al, bb));
    const float m1 = fmaxf(fmaf(r1.x, al, bb), fmaf(r1.y, al, bb));
    out[pid] = fmaxf(fmaxf(m0, m1), 0.f);
}

// ---------------------------------------------------------------------------
extern "C" void kernel_launch(void* const* d_in, const int* in_sizes, int n_in,
                              void* d_out, int out_size, void* d_ws, size_t ws_size,
                              hipStream_t stream)
{
    const float* x     = (const float*)d_in[0];
    const float* w_off = (const float*)d_in[1];
    const float* b_off = (const float*)d_in[2];
    const float* w_def = (const float*)d_in[3];
    const float* b_def = (const float*)d_in[4];
    const float* gamma = (const float*)d_in[5];
    const float* beta  = (const float*)d_in[6];
    const float* fc1_w = (const float*)d_in[7];
    const float* fc1_b = (const float*)d_in[8];
    const float* fc2_w = (const float*)d_in[9];
    const float* fc2_b = (const float*)d_in[10];
    float* out = (float*)d_out;

    float* ws    = (float*)d_ws;
    float* offs  = ws;                           // 4*18*HW = 2,654,208 floats
    float* yb    = ws + 2654208;                 // 4*64*HW = 9,437,184 floats
    float* stats = yb + 9437184;                 // 1024 floats
    float* sum_bc   = stats;                     // 256
    float* sumsq_bc = stats + 256;               // 256
    float* alpha    = stats + 512;               // 256
    float* bbias    = stats + 768;               // 256

    k_conv_off<<<dim3(NPIX_ / 256), dim3(256), 0, stream>>>(x, w_off, b_off, offs, stats);
    k_deform  <<<dim3(NPIX_ / 256), dim3(256), 0, stream>>>(x, offs, w_def, b_def, yb);
    k_stats   <<<dim3(B_ * COUT_ * HW_ / 256), dim3(256), 0, stream>>>(yb, sum_bc, sumsq_bc);
    k_se      <<<dim3(1), dim3(256), 0, stream>>>(sum_bc, sumsq_bc, gamma, beta,
                                                  fc1_w, fc1_b, fc2_w, fc2_b, alpha, bbias);
    k_finish  <<<dim3(B_ * COUT_ * 96 * 96 / 256), dim3(256), 0, stream>>>(yb, alpha, bbias, out);
}

// Round 2
// 462.769 us; speedup vs baseline: 1.8440x; 1.8440x over previous
//
#include <hip/hip_runtime.h>
#include <math.h>

#define B_    4
#define CIN_  32
#define COUT_ 64
#define H_    192
#define W_    192
#define HW_   (H_ * W_)        // 36864
#define NPIX_ (B_ * HW_)       // 147456
#define EPS_  1e-5f

// unaligned-safe float2 load (addresses are only 4B-aligned in general)
static __device__ __forceinline__ float2 ld2u(const float* p) {
    float2 r; __builtin_memcpy(&r, p, 8); return r;
}

// ---------------------------------------------------------------------------
// Kernel 1: offsets = conv3x3_same(x, w_off) + b_off   (32 -> 18 channels)
// TWO pixels per thread (adjacent in w; W even so pairs never straddle rows).
// Per kk: batch-load all 32 channel float2s, then FMA burst from LDS weights.
// Also zeroes the stats accumulators (block 0).
// ---------------------------------------------------------------------------
__global__ __launch_bounds__(256, 4) void k_conv_off(
    const float* __restrict__ x, const float* __restrict__ w_off,
    const float* __restrict__ b_off, float* __restrict__ offs,
    float* __restrict__ stats)
{
    __shared__ float wl[9 * 32 * 20];   // [kk][ci][o], rows padded 18->20
    const int tid = threadIdx.x;
    for (int d = tid; d < 9 * 32 * 18; d += 256) {
        int o  = d % 18;
        int t2 = d / 18;
        int ci = t2 % 32;
        int kk = t2 / 32;
        wl[(kk * 32 + ci) * 20 + o] = w_off[(o * 32 + ci) * 9 + kk];
    }
    for (int d = tid; d < 9 * 32; d += 256) {
        wl[d * 20 + 18] = 0.f;
        wl[d * 20 + 19] = 0.f;
    }
    if (blockIdx.x == 0) {
        for (int d = tid; d < 512; d += 256) stats[d] = 0.f;
    }
    __syncthreads();

    const int pp  = blockIdx.x * 256 + tid;   // pixel-pair id < 73728
    const int pid = pp * 2;
    const int b   = pid / HW_;
    const int rem = pid - b * HW_;
    const int h   = rem / W_;
    const int w   = rem - h * W_;             // even

    float acc0[20], acc1[20];
#pragma unroll
    for (int o = 0; o < 20; ++o) { acc0[o] = 0.f; acc1[o] = 0.f; }

    const float* xb = x + b * CIN_ * HW_;

#pragma unroll 1
    for (int kk = 0; kk < 9; ++kk) {
        const int yy = h + kk / 3 - 1;
        if (yy < 0 || yy >= H_) continue;     // zero pad (both pixels)
        const int sx = w + kk % 3 - 1;        // tap x for pixel0; pixel1 = sx+1
        const int bx = min(max(sx, 0), W_ - 2);
        const float* rowp = xb + yy * W_ + bx;
        const bool p0_in  = (sx >= 0);            // sx <= 191 always
        const bool p0_lo  = (sx <= W_ - 2);       // pixel0 takes .x
        const bool p1_in  = (sx <= W_ - 2);       // sx+1 <= 191
        // pixel1 takes .y unless sx == -1 (then bx==0, value at .x)

#pragma unroll 1
        for (int c0 = 0; c0 < 32; c0 += 16) {
            float va[16], vb[16];
#pragma unroll
            for (int c = 0; c < 16; ++c) {
                float2 p = ld2u(rowp + (c0 + c) * HW_);
                va[c] = p0_in ? (p0_lo ? p.x : p.y) : 0.f;
                vb[c] = p1_in ? ((sx >= 0) ? p.y : p.x) : 0.f;
            }
#pragma unroll
            for (int c = 0; c < 16; ++c) {
                const float4* wr = (const float4*)&wl[(kk * 32 + c0 + c) * 20];
                const float a = va[c], bv = vb[c];
#pragma unroll
                for (int q = 0; q < 5; ++q) {
                    float4 wv = wr[q];
                    acc0[q * 4 + 0] += a * wv.x;  acc1[q * 4 + 0] += bv * wv.x;
                    acc0[q * 4 + 1] += a * wv.y;  acc1[q * 4 + 1] += bv * wv.y;
                    acc0[q * 4 + 2] += a * wv.z;  acc1[q * 4 + 2] += bv * wv.z;
                    acc0[q * 4 + 3] += a * wv.w;  acc1[q * 4 + 3] += bv * wv.w;
                }
            }
        }
    }

#pragma unroll
    for (int o = 0; o < 18; ++o) {
        const float bo = b_off[o];
        float2 st; st.x = acc0[o] + bo; st.y = acc1[o] + bo;
        *(float2*)(offs + (b * 18 + o) * HW_ + rem) = st;   // rem even -> 8B aligned
    }
}

// ---------------------------------------------------------------------------
// Kernel 2: deformable conv. 512 threads/block (2 blocks/CU with 73.7KB LDS
// -> 16 waves/CU). One thread per pixel, acc[64]. Per kk: batch-compute
// bilinear samples v[16] (paired-corner float2 loads, 32 loads in flight),
// then pure FMA burst on LDS-broadcast weights.
// ---------------------------------------------------------------------------
__global__ __launch_bounds__(512, 4) void k_deform(
    const float* __restrict__ x, const float* __restrict__ offs,
    const float* __restrict__ w_def, const float* __restrict__ b_def,
    float* __restrict__ y)
{
    __shared__ float wl[9 * 32 * 64];   // [kk][c][o], 73728 B
    const int tid = threadIdx.x;
    for (int d = tid; d < 9 * 32 * 64; d += 512) {
        int o  = d & 63;
        int t2 = d >> 6;
        int c  = t2 % 32;
        int kk = t2 / 32;
        wl[d] = w_def[(o * 32 + c) * 9 + kk];
    }
    __syncthreads();

    const int pid = blockIdx.x * 512 + tid;
    const int b   = pid / HW_;
    const int rem = pid - b * HW_;
    const int h   = rem / W_;
    const int w   = rem - h * W_;

    float acc[64];
#pragma unroll
    for (int o = 0; o < 64; ++o) acc[o] = 0.f;

    const float* xb = x + b * CIN_ * HW_;
    const float* ob = offs + b * 18 * HW_ + rem;

#pragma unroll 1
    for (int kk = 0; kk < 9; ++kk) {
        const float dy = ob[(2 * kk) * HW_];
        const float dx = ob[(2 * kk + 1) * HW_];
        const float py = (float)(h + kk / 3 - 1) + dy;
        const float px = (float)(w + kk % 3 - 1) + dx;
        const float y0f = floorf(py), x0f = floorf(px);
        const float wy = py - y0f, wx = px - x0f;
        const int iy0 = (int)y0f, ix0 = (int)x0f;
        const int iy1 = iy0 + 1,  ix1 = ix0 + 1;
        const float vy0 = (iy0 >= 0 && iy0 < H_) ? 1.f : 0.f;
        const float vy1 = (iy1 >= 0 && iy1 < H_) ? 1.f : 0.f;
        const float vx0 = (ix0 >= 0 && ix0 < W_) ? 1.f : 0.f;
        const float vx1 = (ix1 >= 0 && ix1 < W_) ? 1.f : 0.f;
        const float w00 = (1.f - wy) * (1.f - wx) * vy0 * vx0;
        const float w01 = (1.f - wy) * wx * vy0 * vx1;
        const float w10 = wy * (1.f - wx) * vy1 * vx0;
        const float w11 = wy * wx * vy1 * vx1;
        const int cy0 = min(max(iy0, 0), H_ - 1), cy1 = min(max(iy1, 0), H_ - 1);
        const int cx0 = min(max(ix0, 0), W_ - 1), cx1 = min(max(ix1, 0), W_ - 1);
        const int bx  = min(cx0, W_ - 2);         // float2 base; cx0,cx1 in {bx,bx+1}
        const int r0  = cy0 * W_ + bx;
        const int r1  = cy1 * W_ + bx;
        const bool s0x = (cx0 == bx);
        const bool s1x = (cx1 == bx);
        const float* wbase = &wl[kk * 32 * 64];

#pragma unroll 1
        for (int c0 = 0; c0 < 32; c0 += 16) {
            float v[16];
#pragma unroll
            for (int c = 0; c < 16; ++c) {
                const float* xc = xb + (c0 + c) * HW_;
                float2 p0 = ld2u(xc + r0);
                float2 p1 = ld2u(xc + r1);
                const float a00 = s0x ? p0.x : p0.y;
                const float a01 = s1x ? p0.x : p0.y;
                const float a10 = s0x ? p1.x : p1.y;
                const float a11 = s1x ? p1.x : p1.y;
                v[c] = w00 * a00 + w01 * a01 + w10 * a10 + w11 * a11;
            }
#pragma unroll
            for (int c = 0; c < 16; ++c) {
                const float4* wr = (const float4*)(wbase + (c0 + c) * 64);
                const float vc = v[c];
#pragma unroll
                for (int q = 0; q < 16; ++q) {
                    float4 wv = wr[q];
                    acc[q * 4 + 0] += vc * wv.x;
                    acc[q * 4 + 1] += vc * wv.y;
                    acc[q * 4 + 2] += vc * wv.z;
                    acc[q * 4 + 3] += vc * wv.w;
                }
            }
        }
    }

    float* yp = y + b * COUT_ * HW_ + rem;
#pragma unroll
    for (int o = 0; o < 64; ++o) yp[o * HW_] = acc[o] + b_def[o];
}

// ---------------------------------------------------------------------------
// Kernel 3: per-(b,c) sum and sum-of-squares of y.
// ---------------------------------------------------------------------------
__global__ __launch_bounds__(256) void k_stats(
    const float* __restrict__ y,
    float* __restrict__ sum_bc, float* __restrict__ sumsq_bc)
{
    const int pid = blockIdx.x * 256 + threadIdx.x;
    const float v = y[pid];
    float s = v, q = v * v;
#pragma unroll
    for (int off = 32; off; off >>= 1) {
        s += __shfl_xor(s, off, 64);
        q += __shfl_xor(q, off, 64);
    }
    __shared__ float ls[4], lq[4];
    const int lane = threadIdx.x & 63, wid = threadIdx.x >> 6;
    if (lane == 0) { ls[wid] = s; lq[wid] = q; }
    __syncthreads();
    if (threadIdx.x == 0) {
        const float ts = ls[0] + ls[1] + ls[2] + ls[3];
        const float tq = lq[0] + lq[1] + lq[2] + lq[3];
        const int bc = pid / HW_;
        atomicAdd(&sum_bc[bc], ts);
        atomicAdd(&sumsq_bc[bc], tq);
    }
}

// ---------------------------------------------------------------------------
// Kernel 4 (1 block): BN stats + SE MLP -> per-(b,c) affine alpha/bbias.
// ---------------------------------------------------------------------------
__global__ __launch_bounds__(256) void k_se(
    const float* __restrict__ sum_bc, const float* __restrict__ sumsq_bc,
    const float* __restrict__ gamma, const float* __restrict__ beta,
    const float* __restrict__ fc1_w, const float* __restrict__ fc1_b,
    const float* __restrict__ fc2_w, const float* __restrict__ fc2_b,
    float* __restrict__ alpha, float* __restrict__ bbias)
{
    const int tid = threadIdx.x;
    const int b = tid >> 6, c = tid & 63;

    float ch_s = 0.f, ch_q = 0.f;
#pragma unroll
    for (int bb = 0; bb < 4; ++bb) {
        ch_s += sum_bc[bb * 64 + c];
        ch_q += sumsq_bc[bb * 64 + c];
    }
    const float invN = 1.f / (float)(B_ * HW_);
    const float mean = ch_s * invN;
    const float var  = ch_q * invN - mean * mean;
    const float a    = gamma[c] * rsqrtf(var + EPS_);
    const float bi   = beta[c] - mean * a;

    __shared__ float sin_[256];
    sin_[tid] = a * (sum_bc[tid] * (1.f / (float)HW_)) + bi;
    __syncthreads();

    float hv[4];
#pragma unroll
    for (int j = 0; j < 4; ++j) {
        float hs = fc1_b[j];
        for (int cc = 0; cc < 64; ++cc) hs += sin_[b * 64 + cc] * fc1_w[j * 64 + cc];
        hv[j] = fmaxf(hs, 0.f);
    }
    float o = fc2_b[c];
#pragma unroll
    for (int j = 0; j < 4; ++j) o += hv[j] * fc2_w[c * 4 + j];
    const float s = 1.f / (1.f + expf(-o));

    alpha[tid] = a * s;
    bbias[tid] = bi * s;
}

// ---------------------------------------------------------------------------
// Kernel 5: fused affine(BN*SE) + ReLU + 2x2 maxpool -> out (4,64,96,96).
// ---------------------------------------------------------------------------
__global__ __launch_bounds__(256) void k_finish(
    const float* __restrict__ y,
    const float* __restrict__ alpha, const float* __restrict__ bbias,
    float* __restrict__ out)
{
    const int pid = blockIdx.x * 256 + threadIdx.x;
    const int bc  = pid / (96 * 96);
    const int rem = pid - bc * (96 * 96);
    const int oh  = rem / 96, ow = rem - oh * 96;
    const float al = alpha[bc], bb = bbias[bc];
    const float* yp = y + bc * HW_ + (2 * oh) * W_ + 2 * ow;
    const float2 r0 = *(const float2*)yp;
    const float2 r1 = *(const float2*)(yp + W_);
    const float m0 = fmaxf(fmaf(r0.x, al, bb), fmaf(r0.y, al, bb));
    const float m1 = fmaxf(fmaf(r1.x, al, bb), fmaf(r1.y, al, bb));
    out[pid] = fmaxf(fmaxf(m0, m1), 0.f);
}

// ---------------------------------------------------------------------------
extern "C" void kernel_launch(void* const* d_in, const int* in_sizes, int n_in,
                              void* d_out, int out_size, void* d_ws, size_t ws_size,
                              hipStream_t stream)
{
    const float* x     = (const float*)d_in[0];
    const float* w_off = (const float*)d_in[1];
    const float* b_off = (const float*)d_in[2];
    const float* w_def = (const float*)d_in[3];
    const float* b_def = (const float*)d_in[4];
    const float* gamma = (const float*)d_in[5];
    const float* beta  = (const float*)d_in[6];
    const float* fc1_w = (const float*)d_in[7];
    const float* fc1_b = (const float*)d_in[8];
    const float* fc2_w = (const float*)d_in[9];
    const float* fc2_b = (const float*)d_in[10];
    float* out = (float*)d_out;

    float* ws    = (float*)d_ws;
    float* offs  = ws;                           // 4*18*HW = 2,654,208 floats
    float* yb    = ws + 2654208;                 // 4*64*HW = 9,437,184 floats
    float* stats = yb + 9437184;                 // 1024 floats
    float* sum_bc   = stats;
    float* sumsq_bc = stats + 256;
    float* alpha    = stats + 512;
    float* bbias    = stats + 768;

    k_conv_off<<<dim3(NPIX_ / 512), dim3(256), 0, stream>>>(x, w_off, b_off, offs, stats);
    k_deform  <<<dim3(NPIX_ / 512), dim3(512), 0, stream>>>(x, offs, w_def, b_def, yb);
    k_stats   <<<dim3(B_ * COUT_ * HW_ / 256), dim3(256), 0, stream>>>(yb, sum_bc, sumsq_bc);
    k_se      <<<dim3(1), dim3(256), 0, stream>>>(sum_bc, sumsq_bc, gamma, beta,
                                                  fc1_w, fc1_b, fc2_w, fc2_b, alpha, bbias);
    k_finish  <<<dim3(B_ * COUT_ * 96 * 96 / 256), dim3(256), 0, stream>>>(yb, alpha, bbias, out);
}

// Round 3
// 374.326 us; speedup vs baseline: 2.2797x; 1.2363x over previous
//
#include <hip/hip_runtime.h>
#include <math.h>

#define B_    4
#define CIN_  32
#define COUT_ 64
#define H_    192
#define W_    192
#define HW_   (H_ * W_)        // 36864
#define NPIX_ (B_ * HW_)       // 147456
#define EPS_  1e-5f

// unaligned-safe float2 load (addresses are only 4B-aligned in general)
static __device__ __forceinline__ float2 ld2u(const float* p) {
    float2 r; __builtin_memcpy(&r, p, 8); return r;
}

// ---------------------------------------------------------------------------
// Kernel 0: prep. Transpose w_def (O,C,3,3) -> wt_def[kk][c][64] and
// w_off (18,C,3,3) -> wt_off[kk][c][20] (rows padded 18->20, zeros).
// Also zeroes the stats accumulators. Uniform-indexed reads of these
// transposed buffers in the conv kernels become scalar (s_load) traffic.
// ---------------------------------------------------------------------------
__global__ __launch_bounds__(256) void k_prep(
    const float* __restrict__ w_def, const float* __restrict__ w_off,
    float* __restrict__ wt_def, float* __restrict__ wt_off,
    float* __restrict__ stats)
{
    const int i = blockIdx.x * 256 + threadIdx.x;
    if (i < 18432) {                       // wt_def[kk][c][o]
        const int o  = i & 63;
        const int c  = (i >> 6) & 31;
        const int kk = i >> 11;
        wt_def[i] = w_def[(o * 32 + c) * 9 + kk];
    } else if (i < 18432 + 5760) {         // wt_off[kk][c][o20]
        const int e  = i - 18432;
        const int o  = e % 20;
        const int t  = e / 20;
        const int c  = t & 31;
        const int kk = t >> 5;
        wt_off[e] = (o < 18) ? w_off[(o * 32 + c) * 9 + kk] : 0.f;
    } else if (i < 18432 + 5760 + 512) {
        stats[i - 18432 - 5760] = 0.f;
    }
}

// ---------------------------------------------------------------------------
// Kernel 1: offsets = conv3x3_same(x, w_off) + b_off (32 -> 18 ch).
// One thread per pixel, no LDS; weights read uniform (scalar path).
// ---------------------------------------------------------------------------
__global__ __launch_bounds__(256, 2) void k_conv_off(
    const float* __restrict__ x, const float* __restrict__ wt,
    const float* __restrict__ b_off, float* __restrict__ offs)
{
    const int pid = blockIdx.x * 256 + threadIdx.x;   // < 147456
    const int b   = pid / HW_;
    const int rem = pid - b * HW_;
    const int h   = rem / W_;
    const int w   = rem - h * W_;

    float acc[20];
#pragma unroll
    for (int o = 0; o < 20; ++o) acc[o] = 0.f;

    const float* xb = x + b * CIN_ * HW_;

#pragma unroll 1
    for (int kk = 0; kk < 9; ++kk) {
        const int yy = h + kk / 3 - 1;
        const int sx = w + kk % 3 - 1;
        const bool okr = (yy >= 0) & (yy < H_);
        const bool okc = (sx >= 0) & (sx < W_);
        const float* rowp = xb + (okr ? yy : 0) * W_ + min(max(sx, 0), W_ - 1);
        const float gate = (okr & okc) ? 1.f : 0.f;

        float va[32];
#pragma unroll
        for (int c = 0; c < 32; ++c) va[c] = rowp[c * HW_] * gate;

#pragma unroll
        for (int c = 0; c < 32; ++c) {
            const float4* wr = (const float4*)(wt + (kk * 32 + c) * 20);
            const float a = va[c];
#pragma unroll
            for (int q = 0; q < 5; ++q) {
                float4 wv = wr[q];
                acc[q * 4 + 0] += a * wv.x;
                acc[q * 4 + 1] += a * wv.y;
                acc[q * 4 + 2] += a * wv.z;
                acc[q * 4 + 3] += a * wv.w;
            }
        }
    }

#pragma unroll
    for (int o = 0; o < 18; ++o)
        offs[(b * 18 + o) * HW_ + rem] = acc[o] + b_off[o];
}

// ---------------------------------------------------------------------------
// Kernel 2: deformable conv. One thread per pixel, acc[64], no LDS.
// Per kk: batch bilinear samples v[16] (64 loads in flight), then a pure
// v_fma burst with weights from uniform (scalar) loads of wt_def.
// ---------------------------------------------------------------------------
__global__ __launch_bounds__(256, 2) void k_deform(
    const float* __restrict__ x, const float* __restrict__ offs,
    const float* __restrict__ wt, const float* __restrict__ b_def,
    float* __restrict__ y)
{
    const int pid = blockIdx.x * 256 + threadIdx.x;
    const int b   = pid / HW_;
    const int rem = pid - b * HW_;
    const int h   = rem / W_;
    const int w   = rem - h * W_;

    float acc[64];
#pragma unroll
    for (int o = 0; o < 64; ++o) acc[o] = 0.f;

    const float* xb = x + b * CIN_ * HW_;
    const float* ob = offs + b * 18 * HW_ + rem;

#pragma unroll 1
    for (int kk = 0; kk < 9; ++kk) {
        const float dy = ob[(2 * kk) * HW_];
        const float dx = ob[(2 * kk + 1) * HW_];
        const float py = (float)(h + kk / 3 - 1) + dy;
        const float px = (float)(w + kk % 3 - 1) + dx;
        const float y0f = floorf(py), x0f = floorf(px);
        const float wy = py - y0f, wx = px - x0f;
        const int iy0 = (int)y0f, ix0 = (int)x0f;
        const int iy1 = iy0 + 1,  ix1 = ix0 + 1;
        const float vy0 = (iy0 >= 0 && iy0 < H_) ? 1.f : 0.f;
        const float vy1 = (iy1 >= 0 && iy1 < H_) ? 1.f : 0.f;
        const float vx0 = (ix0 >= 0 && ix0 < W_) ? 1.f : 0.f;
        const float vx1 = (ix1 >= 0 && ix1 < W_) ? 1.f : 0.f;
        const float w00 = (1.f - wy) * (1.f - wx) * vy0 * vx0;
        const float w01 = (1.f - wy) * wx * vy0 * vx1;
        const float w10 = wy * (1.f - wx) * vy1 * vx0;
        const float w11 = wy * wx * vy1 * vx1;
        const int cy0 = min(max(iy0, 0), H_ - 1), cy1 = min(max(iy1, 0), H_ - 1);
        const int cx0 = min(max(ix0, 0), W_ - 1), cx1 = min(max(ix1, 0), W_ - 1);
        const int bx  = min(cx0, W_ - 2);       // float2 base; cx0,cx1 in {bx,bx+1}
        const int r0  = cy0 * W_ + bx;
        const int r1  = cy1 * W_ + bx;
        const bool s0x = (cx0 == bx);
        const bool s1x = (cx1 == bx);

#pragma unroll 1
        for (int c0 = 0; c0 < 32; c0 += 16) {
            float v[16];
#pragma unroll
            for (int c = 0; c < 16; ++c) {
                const float* xc = xb + (c0 + c) * HW_;
                float2 p0 = ld2u(xc + r0);
                float2 p1 = ld2u(xc + r1);
                const float a00 = s0x ? p0.x : p0.y;
                const float a01 = s1x ? p0.x : p0.y;
                const float a10 = s0x ? p1.x : p1.y;
                const float a11 = s1x ? p1.x : p1.y;
                v[c] = w00 * a00 + w01 * a01 + w10 * a10 + w11 * a11;
            }
#pragma unroll
            for (int c = 0; c < 16; ++c) {
                const float4* wr = (const float4*)(wt + ((kk * 32 + c0 + c) << 6));
                const float vc = v[c];
#pragma unroll
                for (int q = 0; q < 16; ++q) {
                    float4 wv = wr[q];
                    acc[q * 4 + 0] += vc * wv.x;
                    acc[q * 4 + 1] += vc * wv.y;
                    acc[q * 4 + 2] += vc * wv.z;
                    acc[q * 4 + 3] += vc * wv.w;
                }
            }
        }
    }

    float* yp = y + b * COUT_ * HW_ + rem;
#pragma unroll
    for (int o = 0; o < 64; ++o) yp[o * HW_] = acc[o] + b_def[o];
}

// ---------------------------------------------------------------------------
// Kernel 3: per-(b,c) sum / sum-of-squares of y, float4 loads.
// Each block covers 1024 consecutive elems, inside one (b,c) plane.
// ---------------------------------------------------------------------------
__global__ __launch_bounds__(256) void k_stats(
    const float* __restrict__ y,
    float* __restrict__ sum_bc, float* __restrict__ sumsq_bc)
{
    const int i = blockIdx.x * 256 + threadIdx.x;
    const float4 v = ((const float4*)y)[i];
    float s = v.x + v.y + v.z + v.w;
    float q = v.x * v.x + v.y * v.y + v.z * v.z + v.w * v.w;
#pragma unroll
    for (int off = 32; off; off >>= 1) {
        s += __shfl_xor(s, off, 64);
        q += __shfl_xor(q, off, 64);
    }
    __shared__ float ls[4], lq[4];
    const int lane = threadIdx.x & 63, wid = threadIdx.x >> 6;
    if (lane == 0) { ls[wid] = s; lq[wid] = q; }
    __syncthreads();
    if (threadIdx.x == 0) {
        const float ts = ls[0] + ls[1] + ls[2] + ls[3];
        const float tq = lq[0] + lq[1] + lq[2] + lq[3];
        const int bc = (i * 4) / HW_;   // uniform within block
        atomicAdd(&sum_bc[bc], ts);
        atomicAdd(&sumsq_bc[bc], tq);
    }
}

// ---------------------------------------------------------------------------
// Kernel 4 (1 block): BN stats + SE MLP -> per-(b,c) affine alpha/bbias.
// ---------------------------------------------------------------------------
__global__ __launch_bounds__(256) void k_se(
    const float* __restrict__ sum_bc, const float* __restrict__ sumsq_bc,
    const float* __restrict__ gamma, const float* __restrict__ beta,
    const float* __restrict__ fc1_w, const float* __restrict__ fc1_b,
    const float* __restrict__ fc2_w, const float* __restrict__ fc2_b,
    float* __restrict__ alpha, float* __restrict__ bbias)
{
    const int tid = threadIdx.x;
    const int b = tid >> 6, c = tid & 63;

    float ch_s = 0.f, ch_q = 0.f;
#pragma unroll
    for (int bb = 0; bb < 4; ++bb) {
        ch_s += sum_bc[bb * 64 + c];
        ch_q += sumsq_bc[bb * 64 + c];
    }
    const float invN = 1.f / (float)(B_ * HW_);
    const float mean = ch_s * invN;
    const float var  = ch_q * invN - mean * mean;
    const float a    = gamma[c] * rsqrtf(var + EPS_);
    const float bi   = beta[c] - mean * a;

    __shared__ float sin_[256];
    sin_[tid] = a * (sum_bc[tid] * (1.f / (float)HW_)) + bi;
    __syncthreads();

    float hv[4];
#pragma unroll
    for (int j = 0; j < 4; ++j) {
        float hs = fc1_b[j];
        for (int cc = 0; cc < 64; ++cc) hs += sin_[b * 64 + cc] * fc1_w[j * 64 + cc];
        hv[j] = fmaxf(hs, 0.f);
    }
    float o = fc2_b[c];
#pragma unroll
    for (int j = 0; j < 4; ++j) o += hv[j] * fc2_w[c * 4 + j];
    const float s = 1.f / (1.f + expf(-o));

    alpha[tid] = a * s;
    bbias[tid] = bi * s;
}

// ---------------------------------------------------------------------------
// Kernel 5: fused affine(BN*SE) + ReLU + 2x2 maxpool. Two outputs/thread,
// float4 row loads, float2 store.
// ---------------------------------------------------------------------------
__global__ __launch_bounds__(256) void k_finish(
    const float* __restrict__ y,
    const float* __restrict__ alpha, const float* __restrict__ bbias,
    float* __restrict__ out)
{
    const int t    = blockIdx.x * 256 + threadIdx.x;  // 2 outputs each
    const int opix = t * 2;
    const int bc   = opix / (96 * 96);
    const int rem  = opix - bc * (96 * 96);
    const int oh   = rem / 96, ow = rem - oh * 96;    // ow even
    const float al = alpha[bc], bb = bbias[bc];
    const float* yp = y + bc * HW_ + (2 * oh) * W_ + 2 * ow;
    const float4 r0 = *(const float4*)yp;
    const float4 r1 = *(const float4*)(yp + W_);
    float2 st;
    st.x = fmaxf(fmaxf(fmaxf(fmaf(r0.x, al, bb), fmaf(r0.y, al, bb)),
                       fmaxf(fmaf(r1.x, al, bb), fmaf(r1.y, al, bb))), 0.f);
    st.y = fmaxf(fmaxf(fmaxf(fmaf(r0.z, al, bb), fmaf(r0.w, al, bb)),
                       fmaxf(fmaf(r1.z, al, bb), fmaf(r1.w, al, bb))), 0.f);
    *(float2*)(out + opix) = st;
}

// ---------------------------------------------------------------------------
extern "C" void kernel_launch(void* const* d_in, const int* in_sizes, int n_in,
                              void* d_out, int out_size, void* d_ws, size_t ws_size,
                              hipStream_t stream)
{
    const float* x     = (const float*)d_in[0];
    const float* w_off = (const float*)d_in[1];
    const float* b_off = (const float*)d_in[2];
    const float* w_def = (const float*)d_in[3];
    const float* b_def = (const float*)d_in[4];
    const float* gamma = (const float*)d_in[5];
    const float* beta  = (const float*)d_in[6];
    const float* fc1_w = (const float*)d_in[7];
    const float* fc1_b = (const float*)d_in[8];
    const float* fc2_w = (const float*)d_in[9];
    const float* fc2_b = (const float*)d_in[10];
    float* out = (float*)d_out;

    float* ws   = (float*)d_ws;
    float* offs = ws;                            // 4*18*HW = 2,654,208 floats
    float* yb   = ws + 2654208;                  // 4*64*HW = 9,437,184 floats
    // small arrays from the END of ws (avoids assuming exact ws_size)
    float* tail    = ws + (ws_size / sizeof(float));
    float* wt_off  = tail - 5760;                // [9][32][20]
    float* wt_def  = wt_off - 18432;             // [9][32][64]
    float* stats   = wt_def - 1024;
    float* sum_bc   = stats;
    float* sumsq_bc = stats + 256;
    float* alpha    = stats + 512;
    float* bbias    = stats + 768;

    k_prep    <<<dim3(97),            dim3(256), 0, stream>>>(w_def, w_off, wt_def, wt_off, stats);
    k_conv_off<<<dim3(NPIX_ / 256),   dim3(256), 0, stream>>>(x, wt_off, b_off, offs);
    k_deform  <<<dim3(NPIX_ / 256),   dim3(256), 0, stream>>>(x, offs, wt_def, b_def, yb);
    k_stats   <<<dim3(NPIX_ * 64 / 1024), dim3(256), 0, stream>>>(yb, sum_bc, sumsq_bc);
    k_se      <<<dim3(1),             dim3(256), 0, stream>>>(sum_bc, sumsq_bc, gamma, beta,
                                                              fc1_w, fc1_b, fc2_w, fc2_b, alpha, bbias);
    k_finish  <<<dim3(B_ * COUT_ * 96 * 96 / 512), dim3(256), 0, stream>>>(yb, alpha, bbias, out);
}